// Round 13
// baseline (74.687 us; speedup 1.0000x reference)
//
#include <hip/hip_runtime.h>

// embedding: (32, 512, 32, 32) f32 ; pixel_shuffle r=4 -> x_ps (32, 32, 128, 128)
// conv 3x3 pad1 (32->32) + BN + ReLU ; head: 32->4 relu -> 1 ; sigmoid
// concat [sig, mask] -> 5x5 conv pad2 (2->1) ; out (32,1,128,128) f32
//
// v13 = v12 + residency round:
//  - 1024 blocks (4-row chunks, 2 ring iterations) so 3 blocks/CU can be
//    resident (LDS 49920*3 = 149760 <= 163840)
//  - VGPR diet: head/BN params loaded per-iteration (L1-hot, v10-proven);
//    bfrag hoist kept. launch_bounds(256,3) -> 3 waves/SIMD, no spill
//  - ORIGINAL staging lane order (coalescing; v11 showed reorder regresses)

typedef __attribute__((ext_vector_type(8))) short short8;
typedef __attribute__((ext_vector_type(4))) float f32x4;

static __device__ __forceinline__ ushort f2bf(float x) {
    union { float f; uint u; } v; v.f = x;
    uint r = v.u + 0x7fffu + ((v.u >> 16) & 1u);   // round-nearest-even
    return (ushort)(r >> 16);
}
static __device__ __forceinline__ uint cvt_pk_bf16(float lo, float hi) {
    uint r;
    asm("v_cvt_pk_bf16_f32 %0, %1, %2" : "=v"(r) : "v"(lo), "v"(hi));
    return r;   // {hi=bf16(hi), lo=bf16(lo)}
}

#define SIG_ELEMS (32 * 128 * 128)
#define BFRAG_OFF (SIG_ELEMS * 4)          // bytes into d_ws, 16B aligned
#define SH_OFF    (BFRAG_OFF + 18432)
#define HDP_OFF   (SH_OFF + 128)           // padded head params [32][144]

// ---- prep: pack B fragments (bf16, BN-scale folded) + shift + head repack ----
__global__ void prep_kernel(const float* __restrict__ conv_w,
                            const float* __restrict__ conv_b,
                            const float* __restrict__ bn_gamma,
                            const float* __restrict__ bn_beta,
                            const float* __restrict__ bn_mean,
                            const float* __restrict__ bn_var,
                            const float* __restrict__ inc,
                            ushort* __restrict__ bfrag,   // [18][64][8]
                            float* __restrict__ shb,      // [32]
                            float* __restrict__ hdp) {    // [32][144]
    int t = blockIdx.x * 256 + threadIdx.x;
    if (t < 9216) {
        int j    = t & 7;
        int lane = (t >> 3) & 63;
        int knt  = t >> 9;          // kk*2 + nt
        int kk   = knt >> 1;
        int nt   = knt & 1;
        int oc   = (lane & 15) + nt * 16;
        int c    = (lane >> 4) * 8 + j;
        float sc = bn_gamma[oc] * rsqrtf(bn_var[oc] + 1e-5f);
        bfrag[t] = f2bf(conv_w[oc * 288 + c * 9 + kk] * sc);
    } else if (t < 9248) {
        int oc = t - 9216;
        float sc = bn_gamma[oc] * rsqrtf(bn_var[oc] + 1e-5f);
        shb[oc] = (conv_b[oc] - bn_mean[oc]) * sc + bn_beta[oc];
    } else if (t < 9248 + 32 * 137) {
        int i = t - 9248;
        int nn = i / 137, r = i - nn * 137;
        hdp[nn * 144 + r] = inc[i];
    }
}

// ---- main: pipelined implicit-GEMM conv + BN + ReLU + head + sigmoid ----
#define PITCHB 8320          // 130 cells * 64 B per staged row
#define NRING  6

__global__ __launch_bounds__(256, 3) void fused_main_kernel(
    const float* __restrict__ emb,      // (32,512,32,32)
    const ushort* __restrict__ bfrag,   // [18][64][8] bf16 (scale-folded)
    const float* __restrict__ shb,      // [32]
    const float* __restrict__ hdp,      // [32][144]
    float* __restrict__ sig_out)        // (32,128,128)
{
    __shared__ __align__(16) char smem[NRING * PITCHB];   // 49920 B

    const int bid = blockIdx.x;
    const int lid = (bid & 7) * 128 + (bid >> 3);  // XCD swizzle (1024 = 8*128)
    const int n   = lid >> 5;     // image 0..31
    const int qc  = lid & 31;     // 4-row chunk 0..31
    const int hq0 = qc << 2;      // first output row

    const int tid  = threadIdx.x;

    // Staging decomposition (v9 order: f fastest -> contiguous 128B / 8 lanes)
    const int f    = tid & 7;
    const int cphi = (tid >> 3) & 3;
    const int sx   = (tid >> 5) & 3;
    const int yy   = tid >> 7;         // 0/1

    // ---- prologue: stage ring rows 0..3 = image rows hq0-1 .. hq0+2 ----
    {
        const int rA = yy, rB = yy + 2;
        const int hA = hq0 + rA - 1, hB = hq0 + rB - 1;
        const bool vA = (unsigned)hA < 128u;
        const bool vB = (unsigned)hB < 128u;
        float4 pA0[4], pA1[4], pB0[4], pB1[4];
        #pragma unroll
        for (int cplo = 0; cplo < 4; ++cplo) {
            pA0[cplo] = make_float4(0.f, 0.f, 0.f, 0.f);
            pA1[cplo] = pA0[cplo]; pB0[cplo] = pA0[cplo]; pB1[cplo] = pA0[cplo];
            if (vA) {
                int cc = cphi * 128 + cplo * 32 + ((hA & 3) << 2) + sx;
                long base = ((long)(n * 512 + cc) << 10) + ((hA >> 2) << 5) + (f << 2);
                pA0[cplo] = *reinterpret_cast<const float4*>(&emb[base]);
                pA1[cplo] = *reinterpret_cast<const float4*>(&emb[base + (16 << 10)]);
            }
            if (vB) {
                int cc = cphi * 128 + cplo * 32 + ((hB & 3) << 2) + sx;
                long base = ((long)(n * 512 + cc) << 10) + ((hB >> 2) << 5) + (f << 2);
                pB0[cplo] = *reinterpret_cast<const float4*>(&emb[base]);
                pB1[cplo] = *reinterpret_cast<const float4*>(&emb[base + (16 << 10)]);
            }
        }
        __builtin_amdgcn_sched_barrier(0);
        // halo-zero columns xi=0,129 for all 6 ring rows (overlaps load latency)
        if (tid < 192) {
            int cell = tid >> 4;       // 0..11
            int wrd  = tid & 15;
            int row  = cell >> 1;
            int col  = (cell & 1) ? 129 : 0;
            ((uint*)smem)[(row * PITCHB + col * 64) / 4 + wrd] = 0u;
        }
        const float a00[4] = {pA0[0].x, pA0[0].y, pA0[0].z, pA0[0].w};
        const float a01[4] = {pA0[1].x, pA0[1].y, pA0[1].z, pA0[1].w};
        const float a02[4] = {pA0[2].x, pA0[2].y, pA0[2].z, pA0[2].w};
        const float a03[4] = {pA0[3].x, pA0[3].y, pA0[3].z, pA0[3].w};
        const float a10[4] = {pA1[0].x, pA1[0].y, pA1[0].z, pA1[0].w};
        const float a11[4] = {pA1[1].x, pA1[1].y, pA1[1].z, pA1[1].w};
        const float a12[4] = {pA1[2].x, pA1[2].y, pA1[2].z, pA1[2].w};
        const float a13[4] = {pA1[3].x, pA1[3].y, pA1[3].z, pA1[3].w};
        const float b00[4] = {pB0[0].x, pB0[0].y, pB0[0].z, pB0[0].w};
        const float b01[4] = {pB0[1].x, pB0[1].y, pB0[1].z, pB0[1].w};
        const float b02[4] = {pB0[2].x, pB0[2].y, pB0[2].z, pB0[2].w};
        const float b03[4] = {pB0[3].x, pB0[3].y, pB0[3].z, pB0[3].w};
        const float b10[4] = {pB1[0].x, pB1[0].y, pB1[0].z, pB1[0].w};
        const float b11[4] = {pB1[1].x, pB1[1].y, pB1[1].z, pB1[1].w};
        const float b12[4] = {pB1[2].x, pB1[2].y, pB1[2].z, pB1[2].w};
        const float b13[4] = {pB1[3].x, pB1[3].y, pB1[3].z, pB1[3].w};
        #pragma unroll
        for (int e = 0; e < 4; ++e) {
            int xi   = 1 + sx + (f << 4) + (e << 2);
            int slot = (cphi ^ ((xi >> 1) ^ (xi >> 4))) & 3;
            int off  = xi * 64 + (slot << 4);
            uint4 qa;
            qa.x = cvt_pk_bf16(a00[e], a10[e]);
            qa.y = cvt_pk_bf16(a01[e], a11[e]);
            qa.z = cvt_pk_bf16(a02[e], a12[e]);
            qa.w = cvt_pk_bf16(a03[e], a13[e]);
            *reinterpret_cast<uint4*>(&smem[rA * PITCHB + off]) = qa;
            uint4 qb;
            qb.x = cvt_pk_bf16(b00[e], b10[e]);
            qb.y = cvt_pk_bf16(b01[e], b11[e]);
            qb.z = cvt_pk_bf16(b02[e], b12[e]);
            qb.w = cvt_pk_bf16(b03[e], b13[e]);
            *reinterpret_cast<uint4*>(&smem[rB * PITCHB + off]) = qb;
        }
    }

    // MFMA-side constants (loop-invariant).
    const int lane = tid & 63;
    const int wv   = tid >> 6;
    const int g    = lane >> 4;    // channel group / oc block -> final tile
    const int m    = lane & 15;    // pixel col within tile
    const int rw   = wv >> 1;      // wave's row within band
    const int xq   = (wv & 1) * 64;
    const int gb0  = g & 1;
    const int gb1  = (g >> 1) & 1;

    int cell_off[4][3];
    #pragma unroll
    for (int t = 0; t < 4; ++t)
        #pragma unroll
        for (int dx = 0; dx < 3; ++dx) {
            int xi = xq + t * 16 + m + dx;
            int slot = (g ^ ((xi >> 1) ^ (xi >> 4))) & 3;
            cell_off[t][dx] = xi * 64 + (slot << 4);
        }

    // Hoisted B fragments: 18 x short8 = 72 VGPRs, loaded ONCE per block.
    short8 bf0[9], bf1[9];
    #pragma unroll
    for (int kk = 0; kk < 9; ++kk) {
        bf0[kk] = *reinterpret_cast<const short8*>(bfrag + (((kk * 2 + 0) * 64 + lane) << 3));
        bf1[kk] = *reinterpret_cast<const short8*>(bfrag + (((kk * 2 + 1) * 64 + lane) << 3));
    }

    const float* hd = hdp + n * 144;

    __syncthreads();

    #pragma unroll 1
    for (int it = 0; it < 2; ++it) {
        // ---- phase A: prefetch the 2 NEW rows (only it=0) ----
        float4 np0[4], np1[4];
        const bool have = (it == 0);
        const int  hn   = hq0 + 3 + yy;
        const bool vn   = have && (hn < 128);
        #pragma unroll
        for (int cplo = 0; cplo < 4; ++cplo) {
            np0[cplo] = make_float4(0.f, 0.f, 0.f, 0.f);
            np1[cplo] = np0[cplo];
            if (vn) {
                int cc = cphi * 128 + cplo * 32 + ((hn & 3) << 2) + sx;
                long base = ((long)(n * 512 + cc) << 10) + ((hn >> 2) << 5) + (f << 2);
                np0[cplo] = *reinterpret_cast<const float4*>(&emb[base]);
                np1[cplo] = *reinterpret_cast<const float4*>(&emb[base + (16 << 10)]);
            }
        }
        __builtin_amdgcn_sched_barrier(0);   // pin loads before compute

        // ---- phase B: compute band it (ring rows 2it+rw+dy, max 5: no wrap) ----
        int rb[3];
        #pragma unroll
        for (int dy = 0; dy < 3; ++dy)
            rb[dy] = (2 * it + rw + dy) * PITCHB;

        f32x4 acc[4][2];
        #pragma unroll
        for (int t = 0; t < 4; ++t)
            #pragma unroll
            for (int nt = 0; nt < 2; ++nt)
                acc[t][nt] = (f32x4){0.f, 0.f, 0.f, 0.f};

        __builtin_amdgcn_s_setprio(1);
        #pragma unroll
        for (int kk = 0; kk < 9; ++kk) {
            const int dy = kk / 3, dxs = kk % 3;
            #pragma unroll
            for (int t = 0; t < 4; ++t) {
                short8 a = *reinterpret_cast<const short8*>(&smem[rb[dy] + cell_off[t][dxs]]);
                acc[t][0] = __builtin_amdgcn_mfma_f32_16x16x32_bf16(bf0[kk], a, acc[t][0], 0, 0, 0);
                acc[t][1] = __builtin_amdgcn_mfma_f32_16x16x32_bf16(bf1[kk], a, acc[t][1], 0, 0, 0);
            }
        }
        __builtin_amdgcn_s_setprio(0);

        // Per-iteration param loads (L1-hot; keeps peak VGPR under the 3-wave cap)
        const f32x4 shA = *reinterpret_cast<const f32x4*>(&shb[g * 4]);
        const f32x4 shB = *reinterpret_cast<const f32x4*>(&shb[16 + g * 4]);
        f32x4 w1A[4], w1B[4];
        #pragma unroll
        for (int o = 0; o < 4; ++o) {
            w1A[o] = *reinterpret_cast<const f32x4*>(&hd[o * 32 + g * 4]);
            w1B[o] = *reinterpret_cast<const f32x4*>(&hd[o * 32 + 16 + g * 4]);
        }
        const f32x4 w2v = *reinterpret_cast<const f32x4*>(&hd[128]);
        const f32x4 b1v = *reinterpret_cast<const f32x4*>(&hd[132]);
        const float b2  = hd[136];

        // Epilogue: BN shift + ReLU, head partials.
        float ph[4][4];
        #pragma unroll
        for (int t = 0; t < 4; ++t) {
            f32x4 vA, vB;
            vA.x = fmaxf(acc[t][0].x + shA.x, 0.f);
            vA.y = fmaxf(acc[t][0].y + shA.y, 0.f);
            vA.z = fmaxf(acc[t][0].z + shA.z, 0.f);
            vA.w = fmaxf(acc[t][0].w + shA.w, 0.f);
            vB.x = fmaxf(acc[t][1].x + shB.x, 0.f);
            vB.y = fmaxf(acc[t][1].y + shB.y, 0.f);
            vB.z = fmaxf(acc[t][1].z + shB.z, 0.f);
            vB.w = fmaxf(acc[t][1].w + shB.w, 0.f);
            #pragma unroll
            for (int o = 0; o < 4; ++o) {
                float p = vA.x * w1A[o].x;
                p = fmaf(vA.y, w1A[o].y, p);
                p = fmaf(vA.z, w1A[o].z, p);
                p = fmaf(vA.w, w1A[o].w, p);
                p = fmaf(vB.x, w1B[o].x, p);
                p = fmaf(vB.y, w1B[o].y, p);
                p = fmaf(vB.z, w1B[o].z, p);
                p = fmaf(vB.w, w1B[o].w, p);
                ph[t][o] = p;
            }
        }

        // Reduce-scatter butterfly (12 shfl): lane ends with tot[o] for tile g.
        float k0[4], k1[4], tot[4];
        #pragma unroll
        for (int o = 0; o < 4; ++o) {
            float send0 = gb0 ? ph[0][o] : ph[1][o];
            float r0 = __shfl_xor(send0, 16);
            k0[o] = (gb0 ? ph[1][o] : ph[0][o]) + r0;
            float send1 = gb0 ? ph[2][o] : ph[3][o];
            float r1 = __shfl_xor(send1, 16);
            k1[o] = (gb0 ? ph[3][o] : ph[2][o]) + r1;
        }
        #pragma unroll
        for (int o = 0; o < 4; ++o) {
            float send = gb1 ? k0[o] : k1[o];
            float r = __shfl_xor(send, 32);
            tot[o] = (gb1 ? k1[o] : k0[o]) + r;
        }

        float q0 = fmaxf(tot[0] + b1v.x, 0.f);
        float q1 = fmaxf(tot[1] + b1v.y, 0.f);
        float q2 = fmaxf(tot[2] + b1v.z, 0.f);
        float q3 = fmaxf(tot[3] + b1v.w, 0.f);
        float yvl = b2;
        yvl = fmaf(w2v.x, q0, yvl);
        yvl = fmaf(w2v.y, q1, yvl);
        yvl = fmaf(w2v.z, q2, yvl);
        yvl = fmaf(w2v.w, q3, yvl);
        float sv = 1.0f / (1.0f + __expf(-yvl));
        sig_out[(n << 14) + ((hq0 + 2 * it + rw) << 7) + xq + lane] = sv;

        // ---- phase C: write the prefetched rows into ring slots 4,5 ----
        if (have) {
            int rs = 4 + yy;
            const float c00[4] = {np0[0].x, np0[0].y, np0[0].z, np0[0].w};
            const float c01[4] = {np0[1].x, np0[1].y, np0[1].z, np0[1].w};
            const float c02[4] = {np0[2].x, np0[2].y, np0[2].z, np0[2].w};
            const float c03[4] = {np0[3].x, np0[3].y, np0[3].z, np0[3].w};
            const float c10[4] = {np1[0].x, np1[0].y, np1[0].z, np1[0].w};
            const float c11[4] = {np1[1].x, np1[1].y, np1[1].z, np1[1].w};
            const float c12[4] = {np1[2].x, np1[2].y, np1[2].z, np1[2].w};
            const float c13[4] = {np1[3].x, np1[3].y, np1[3].z, np1[3].w};
            #pragma unroll
            for (int e = 0; e < 4; ++e) {
                int xi   = 1 + sx + (f << 4) + (e << 2);
                int slot = (cphi ^ ((xi >> 1) ^ (xi >> 4))) & 3;
                uint4 qv;
                qv.x = cvt_pk_bf16(c00[e], c10[e]);
                qv.y = cvt_pk_bf16(c01[e], c11[e]);
                qv.z = cvt_pk_bf16(c02[e], c12[e]);
                qv.w = cvt_pk_bf16(c03[e], c13[e]);
                *reinterpret_cast<uint4*>(&smem[rs * PITCHB + xi * 64 + (slot << 4)]) = qv;
            }
        }
        __syncthreads();
    }
}

// ---- smooth: 5x5, 2ch -> 1ch ----
__global__ __launch_bounds__(256) void smooth_kernel(
    const float* __restrict__ sig,
    const float* __restrict__ masks,
    const float* __restrict__ sw,
    const float* __restrict__ sb,
    float* __restrict__ out)
{
    __shared__ float ls[2][400];

    const int tid  = threadIdx.x;
    const int n    = blockIdx.x >> 6;
    const int tile = blockIdx.x & 63;
    const int h0   = (tile >> 3) << 4;
    const int w0   = (tile & 7) << 4;

    for (int i = tid; i < 800; i += 256) {
        int chn = (i >= 400) ? 1 : 0;
        int r  = i - chn * 400;
        int yy = r / 20;
        int xx = r - yy * 20;
        int h  = h0 + yy - 2;
        int w  = w0 + xx - 2;
        float v = 0.0f;
        if ((unsigned)h < 128u && (unsigned)w < 128u) {
            const float* src = chn ? masks : sig;
            v = src[(n << 14) + (h << 7) + w];
        }
        ls[chn][r] = v;
    }
    __syncthreads();

    const int tx = tid & 15;
    const int ty = tid >> 4;

    float accv = sb[0];
    #pragma unroll
    for (int chn = 0; chn < 2; ++chn)
        #pragma unroll
        for (int dy = 0; dy < 5; ++dy)
            #pragma unroll
            for (int dx = 0; dx < 5; ++dx)
                accv = fmaf(ls[chn][(ty + dy) * 20 + tx + dx],
                            sw[(chn * 5 + dy) * 5 + dx], accv);
    out[(n << 14) + ((h0 + ty) << 7) + (w0 + tx)] = accv;
}

extern "C" void kernel_launch(void* const* d_in, const int* in_sizes, int n_in,
                              void* d_out, int out_size, void* d_ws, size_t ws_size,
                              hipStream_t stream) {
    const float* emb     = (const float*)d_in[0];
    const float* inc     = (const float*)d_in[1];
    const float* masks   = (const float*)d_in[2];
    const float* conv_w  = (const float*)d_in[3];
    const float* conv_b  = (const float*)d_in[4];
    const float* bn_g    = (const float*)d_in[5];
    const float* bn_b    = (const float*)d_in[6];
    const float* bn_m    = (const float*)d_in[7];
    const float* bn_v    = (const float*)d_in[8];
    const float* sw      = (const float*)d_in[9];
    const float* sb      = (const float*)d_in[10];
    float*  out   = (float*)d_out;
    float*  sig   = (float*)d_ws;
    ushort* bfrag = (ushort*)((char*)d_ws + BFRAG_OFF);
    float*  shb   = (float*)((char*)d_ws + SH_OFF);
    float*  hdp   = (float*)((char*)d_ws + HDP_OFF);

    prep_kernel<<<54, 256, 0, stream>>>(conv_w, conv_b, bn_g, bn_b, bn_m, bn_v,
                                        inc, bfrag, shb, hdp);
    fused_main_kernel<<<1024, 256, 0, stream>>>(emb, bfrag, shb, hdp, sig);
    smooth_kernel<<<2048, 256, 0, stream>>>(sig, masks, sw, sb, out);
}

// Round 14
// 32.703 us; speedup vs baseline: 2.2838x; 2.2838x over previous
//
#include <hip/hip_runtime.h>

// embedding: (32, 512, 32, 32) f32 ; pixel_shuffle r=4 -> x_ps (32, 32, 128, 128)
// conv 3x3 pad1 (32->32) + BN + ReLU ; head: 32->4 relu -> 1 ; sigmoid
// concat [sig, mask] -> 5x5 conv pad2 (2->1) ; out (32,1,128,128) f32
//
// FINAL = v12 (champion, 32.86 us): ring-pipelined bf16-MFMA implicit-GEMM
// conv; bfrag hoisted to 72 VGPRs; setprio around MFMA; original staging
// lane order (coalescing); reduce-scatter in-register head; single barrier
// per band. v10/v13 established launch_bounds(256,3) -> 84-VGPR clamp ->
// spill on this toolchain, closing the 3-blocks/CU residency direction.

typedef __attribute__((ext_vector_type(8))) short short8;
typedef __attribute__((ext_vector_type(4))) float f32x4;

static __device__ __forceinline__ ushort f2bf(float x) {
    union { float f; uint u; } v; v.f = x;
    uint r = v.u + 0x7fffu + ((v.u >> 16) & 1u);   // round-nearest-even
    return (ushort)(r >> 16);
}
static __device__ __forceinline__ uint cvt_pk_bf16(float lo, float hi) {
    uint r;
    asm("v_cvt_pk_bf16_f32 %0, %1, %2" : "=v"(r) : "v"(lo), "v"(hi));
    return r;   // {hi=bf16(hi), lo=bf16(lo)}
}

#define SIG_ELEMS (32 * 128 * 128)
#define BFRAG_OFF (SIG_ELEMS * 4)          // bytes into d_ws, 16B aligned
#define SH_OFF    (BFRAG_OFF + 18432)
#define HDP_OFF   (SH_OFF + 128)           // padded head params [32][144]

// ---- prep: pack B fragments (bf16, BN-scale folded) + shift + head repack ----
__global__ void prep_kernel(const float* __restrict__ conv_w,
                            const float* __restrict__ conv_b,
                            const float* __restrict__ bn_gamma,
                            const float* __restrict__ bn_beta,
                            const float* __restrict__ bn_mean,
                            const float* __restrict__ bn_var,
                            const float* __restrict__ inc,
                            ushort* __restrict__ bfrag,   // [18][64][8]
                            float* __restrict__ shb,      // [32]
                            float* __restrict__ hdp) {    // [32][144]
    int t = blockIdx.x * 256 + threadIdx.x;
    if (t < 9216) {
        int j    = t & 7;
        int lane = (t >> 3) & 63;
        int knt  = t >> 9;          // kk*2 + nt
        int kk   = knt >> 1;
        int nt   = knt & 1;
        int oc   = (lane & 15) + nt * 16;
        int c    = (lane >> 4) * 8 + j;
        float sc = bn_gamma[oc] * rsqrtf(bn_var[oc] + 1e-5f);
        bfrag[t] = f2bf(conv_w[oc * 288 + c * 9 + kk] * sc);
    } else if (t < 9248) {
        int oc = t - 9216;
        float sc = bn_gamma[oc] * rsqrtf(bn_var[oc] + 1e-5f);
        shb[oc] = (conv_b[oc] - bn_mean[oc]) * sc + bn_beta[oc];
    } else if (t < 9248 + 32 * 137) {
        int i = t - 9248;
        int nn = i / 137, r = i - nn * 137;
        hdp[nn * 144 + r] = inc[i];
    }
}

// ---- main: pipelined implicit-GEMM conv + BN + ReLU + head + sigmoid ----
#define PITCHB 8320          // 130 cells * 64 B per staged row
#define NRING  6

__global__ __launch_bounds__(256, 2) void fused_main_kernel(
    const float* __restrict__ emb,      // (32,512,32,32)
    const ushort* __restrict__ bfrag,   // [18][64][8] bf16 (scale-folded)
    const float* __restrict__ shb,      // [32]
    const float* __restrict__ hdp,      // [32][144]
    float* __restrict__ sig_out)        // (32,128,128)
{
    __shared__ __align__(16) char smem[NRING * PITCHB];   // 49920 B

    const int bid = blockIdx.x;
    const int lid = (bid & 7) * 64 + (bid >> 3);   // XCD swizzle (512 = 8*64)
    const int n   = lid >> 4;     // image 0..31
    const int q   = lid & 15;     // 8-row chunk 0..15
    const int hq0 = q << 3;       // first output row

    const int tid  = threadIdx.x;

    // Staging decomposition (f fastest -> contiguous 128B per 8 lanes)
    const int f    = tid & 7;
    const int cphi = (tid >> 3) & 3;
    const int sx   = (tid >> 5) & 3;
    const int yy   = tid >> 7;         // 0/1

    // ---- prologue: stage ring rows 0..3 = image rows hq0-1 .. hq0+2 ----
    {
        const int rA = yy, rB = yy + 2;
        const int hA = hq0 + rA - 1, hB = hq0 + rB - 1;
        const bool vA = (unsigned)hA < 128u;
        const bool vB = (unsigned)hB < 128u;
        float4 pA0[4], pA1[4], pB0[4], pB1[4];
        #pragma unroll
        for (int cplo = 0; cplo < 4; ++cplo) {
            pA0[cplo] = make_float4(0.f, 0.f, 0.f, 0.f);
            pA1[cplo] = pA0[cplo]; pB0[cplo] = pA0[cplo]; pB1[cplo] = pA0[cplo];
            if (vA) {
                int cc = cphi * 128 + cplo * 32 + ((hA & 3) << 2) + sx;
                long base = ((long)(n * 512 + cc) << 10) + ((hA >> 2) << 5) + (f << 2);
                pA0[cplo] = *reinterpret_cast<const float4*>(&emb[base]);
                pA1[cplo] = *reinterpret_cast<const float4*>(&emb[base + (16 << 10)]);
            }
            if (vB) {
                int cc = cphi * 128 + cplo * 32 + ((hB & 3) << 2) + sx;
                long base = ((long)(n * 512 + cc) << 10) + ((hB >> 2) << 5) + (f << 2);
                pB0[cplo] = *reinterpret_cast<const float4*>(&emb[base]);
                pB1[cplo] = *reinterpret_cast<const float4*>(&emb[base + (16 << 10)]);
            }
        }
        __builtin_amdgcn_sched_barrier(0);
        // halo-zero columns xi=0,129 for all 6 ring rows (overlaps load latency)
        if (tid < 192) {
            int cell = tid >> 4;       // 0..11
            int wrd  = tid & 15;
            int row  = cell >> 1;
            int col  = (cell & 1) ? 129 : 0;
            ((uint*)smem)[(row * PITCHB + col * 64) / 4 + wrd] = 0u;
        }
        const float a00[4] = {pA0[0].x, pA0[0].y, pA0[0].z, pA0[0].w};
        const float a01[4] = {pA0[1].x, pA0[1].y, pA0[1].z, pA0[1].w};
        const float a02[4] = {pA0[2].x, pA0[2].y, pA0[2].z, pA0[2].w};
        const float a03[4] = {pA0[3].x, pA0[3].y, pA0[3].z, pA0[3].w};
        const float a10[4] = {pA1[0].x, pA1[0].y, pA1[0].z, pA1[0].w};
        const float a11[4] = {pA1[1].x, pA1[1].y, pA1[1].z, pA1[1].w};
        const float a12[4] = {pA1[2].x, pA1[2].y, pA1[2].z, pA1[2].w};
        const float a13[4] = {pA1[3].x, pA1[3].y, pA1[3].z, pA1[3].w};
        const float b00[4] = {pB0[0].x, pB0[0].y, pB0[0].z, pB0[0].w};
        const float b01[4] = {pB0[1].x, pB0[1].y, pB0[1].z, pB0[1].w};
        const float b02[4] = {pB0[2].x, pB0[2].y, pB0[2].z, pB0[2].w};
        const float b03[4] = {pB0[3].x, pB0[3].y, pB0[3].z, pB0[3].w};
        const float b10[4] = {pB1[0].x, pB1[0].y, pB1[0].z, pB1[0].w};
        const float b11[4] = {pB1[1].x, pB1[1].y, pB1[1].z, pB1[1].w};
        const float b12[4] = {pB1[2].x, pB1[2].y, pB1[2].z, pB1[2].w};
        const float b13[4] = {pB1[3].x, pB1[3].y, pB1[3].z, pB1[3].w};
        #pragma unroll
        for (int e = 0; e < 4; ++e) {
            int xi   = 1 + sx + (f << 4) + (e << 2);
            int slot = (cphi ^ ((xi >> 1) ^ (xi >> 4))) & 3;
            int off  = xi * 64 + (slot << 4);
            uint4 qa;
            qa.x = cvt_pk_bf16(a00[e], a10[e]);
            qa.y = cvt_pk_bf16(a01[e], a11[e]);
            qa.z = cvt_pk_bf16(a02[e], a12[e]);
            qa.w = cvt_pk_bf16(a03[e], a13[e]);
            *reinterpret_cast<uint4*>(&smem[rA * PITCHB + off]) = qa;
            uint4 qb;
            qb.x = cvt_pk_bf16(b00[e], b10[e]);
            qb.y = cvt_pk_bf16(b01[e], b11[e]);
            qb.z = cvt_pk_bf16(b02[e], b12[e]);
            qb.w = cvt_pk_bf16(b03[e], b13[e]);
            *reinterpret_cast<uint4*>(&smem[rB * PITCHB + off]) = qb;
        }
    }

    // MFMA-side constants (loop-invariant).
    const int lane = tid & 63;
    const int wv   = tid >> 6;
    const int g    = lane >> 4;    // channel group / oc block -> final tile
    const int m    = lane & 15;    // pixel col within tile
    const int rw   = wv >> 1;      // wave's row within band
    const int xq   = (wv & 1) * 64;
    const int gb0  = g & 1;
    const int gb1  = (g >> 1) & 1;

    int cell_off[4][3];
    #pragma unroll
    for (int t = 0; t < 4; ++t)
        #pragma unroll
        for (int dx = 0; dx < 3; ++dx) {
            int xi = xq + t * 16 + m + dx;
            int slot = (g ^ ((xi >> 1) ^ (xi >> 4))) & 3;
            cell_off[t][dx] = xi * 64 + (slot << 4);
        }

    // Hoisted B fragments: 18 x short8 = 72 VGPRs, loaded ONCE per block.
    short8 bf0[9], bf1[9];
    #pragma unroll
    for (int kk = 0; kk < 9; ++kk) {
        bf0[kk] = *reinterpret_cast<const short8*>(bfrag + (((kk * 2 + 0) * 64 + lane) << 3));
        bf1[kk] = *reinterpret_cast<const short8*>(bfrag + (((kk * 2 + 1) * 64 + lane) << 3));
    }

    // Hoisted head/BN params.
    const float* hd = hdp + n * 144;
    const f32x4 shA = *reinterpret_cast<const f32x4*>(&shb[g * 4]);
    const f32x4 shB = *reinterpret_cast<const f32x4*>(&shb[16 + g * 4]);
    f32x4 w1A[4], w1B[4];
    #pragma unroll
    for (int o = 0; o < 4; ++o) {
        w1A[o] = *reinterpret_cast<const f32x4*>(&hd[o * 32 + g * 4]);
        w1B[o] = *reinterpret_cast<const f32x4*>(&hd[o * 32 + 16 + g * 4]);
    }
    const f32x4 w2v = *reinterpret_cast<const f32x4*>(&hd[128]);
    const f32x4 b1v = *reinterpret_cast<const f32x4*>(&hd[132]);
    const float b2  = hd[136];

    __syncthreads();

    #pragma unroll 1
    for (int it = 0; it < 4; ++it) {
        // ---- phase A: prefetch the 2 NEW rows for band it+1 ----
        float4 np0[4], np1[4];
        const bool have = (it < 3);
        const int  hn   = hq0 + 2 * it + 3 + yy;
        const bool vn   = have && (hn < 128);
        #pragma unroll
        for (int cplo = 0; cplo < 4; ++cplo) {
            np0[cplo] = make_float4(0.f, 0.f, 0.f, 0.f);
            np1[cplo] = np0[cplo];
            if (vn) {
                int cc = cphi * 128 + cplo * 32 + ((hn & 3) << 2) + sx;
                long base = ((long)(n * 512 + cc) << 10) + ((hn >> 2) << 5) + (f << 2);
                np0[cplo] = *reinterpret_cast<const float4*>(&emb[base]);
                np1[cplo] = *reinterpret_cast<const float4*>(&emb[base + (16 << 10)]);
            }
        }
        __builtin_amdgcn_sched_barrier(0);   // pin loads before compute

        // ---- phase B: compute band it ----
        int rb[3];
        #pragma unroll
        for (int dy = 0; dy < 3; ++dy) {
            int r = 2 * it + rw + dy;
            if (r >= NRING) r -= NRING;
            rb[dy] = r * PITCHB;
        }

        f32x4 acc[4][2];
        #pragma unroll
        for (int t = 0; t < 4; ++t)
            #pragma unroll
            for (int nt = 0; nt < 2; ++nt)
                acc[t][nt] = (f32x4){0.f, 0.f, 0.f, 0.f};

        __builtin_amdgcn_s_setprio(1);
        #pragma unroll
        for (int kk = 0; kk < 9; ++kk) {
            const int dy = kk / 3, dxs = kk % 3;
            #pragma unroll
            for (int t = 0; t < 4; ++t) {
                short8 a = *reinterpret_cast<const short8*>(&smem[rb[dy] + cell_off[t][dxs]]);
                acc[t][0] = __builtin_amdgcn_mfma_f32_16x16x32_bf16(bf0[kk], a, acc[t][0], 0, 0, 0);
                acc[t][1] = __builtin_amdgcn_mfma_f32_16x16x32_bf16(bf1[kk], a, acc[t][1], 0, 0, 0);
            }
        }
        __builtin_amdgcn_s_setprio(0);

        // Epilogue: BN shift + ReLU, head partials.
        float ph[4][4];
        #pragma unroll
        for (int t = 0; t < 4; ++t) {
            f32x4 vA, vB;
            vA.x = fmaxf(acc[t][0].x + shA.x, 0.f);
            vA.y = fmaxf(acc[t][0].y + shA.y, 0.f);
            vA.z = fmaxf(acc[t][0].z + shA.z, 0.f);
            vA.w = fmaxf(acc[t][0].w + shA.w, 0.f);
            vB.x = fmaxf(acc[t][1].x + shB.x, 0.f);
            vB.y = fmaxf(acc[t][1].y + shB.y, 0.f);
            vB.z = fmaxf(acc[t][1].z + shB.z, 0.f);
            vB.w = fmaxf(acc[t][1].w + shB.w, 0.f);
            #pragma unroll
            for (int o = 0; o < 4; ++o) {
                float p = vA.x * w1A[o].x;
                p = fmaf(vA.y, w1A[o].y, p);
                p = fmaf(vA.z, w1A[o].z, p);
                p = fmaf(vA.w, w1A[o].w, p);
                p = fmaf(vB.x, w1B[o].x, p);
                p = fmaf(vB.y, w1B[o].y, p);
                p = fmaf(vB.z, w1B[o].z, p);
                p = fmaf(vB.w, w1B[o].w, p);
                ph[t][o] = p;
            }
        }

        // Reduce-scatter butterfly (12 shfl): lane ends with tot[o] for tile g.
        float k0[4], k1[4], tot[4];
        #pragma unroll
        for (int o = 0; o < 4; ++o) {
            float send0 = gb0 ? ph[0][o] : ph[1][o];
            float r0 = __shfl_xor(send0, 16);
            k0[o] = (gb0 ? ph[1][o] : ph[0][o]) + r0;
            float send1 = gb0 ? ph[2][o] : ph[3][o];
            float r1 = __shfl_xor(send1, 16);
            k1[o] = (gb0 ? ph[3][o] : ph[2][o]) + r1;
        }
        #pragma unroll
        for (int o = 0; o < 4; ++o) {
            float send = gb1 ? k0[o] : k1[o];
            float r = __shfl_xor(send, 32);
            tot[o] = (gb1 ? k1[o] : k0[o]) + r;
        }

        float q0 = fmaxf(tot[0] + b1v.x, 0.f);
        float q1 = fmaxf(tot[1] + b1v.y, 0.f);
        float q2 = fmaxf(tot[2] + b1v.z, 0.f);
        float q3 = fmaxf(tot[3] + b1v.w, 0.f);
        float yvl = b2;
        yvl = fmaf(w2v.x, q0, yvl);
        yvl = fmaf(w2v.y, q1, yvl);
        yvl = fmaf(w2v.z, q2, yvl);
        yvl = fmaf(w2v.w, q3, yvl);
        float sv = 1.0f / (1.0f + __expf(-yvl));
        sig_out[(n << 14) + ((hq0 + 2 * it + rw) << 7) + xq + lane] = sv;

        // ---- phase C: write the prefetched rows into ring slots ----
        if (have) {
            int rs = 2 * it + 4 + yy;
            if (rs >= NRING) rs -= NRING;
            const float c00[4] = {np0[0].x, np0[0].y, np0[0].z, np0[0].w};
            const float c01[4] = {np0[1].x, np0[1].y, np0[1].z, np0[1].w};
            const float c02[4] = {np0[2].x, np0[2].y, np0[2].z, np0[2].w};
            const float c03[4] = {np0[3].x, np0[3].y, np0[3].z, np0[3].w};
            const float c10[4] = {np1[0].x, np1[0].y, np1[0].z, np1[0].w};
            const float c11[4] = {np1[1].x, np1[1].y, np1[1].z, np1[1].w};
            const float c12[4] = {np1[2].x, np1[2].y, np1[2].z, np1[2].w};
            const float c13[4] = {np1[3].x, np1[3].y, np1[3].z, np1[3].w};
            #pragma unroll
            for (int e = 0; e < 4; ++e) {
                int xi   = 1 + sx + (f << 4) + (e << 2);
                int slot = (cphi ^ ((xi >> 1) ^ (xi >> 4))) & 3;
                uint4 qv;
                qv.x = cvt_pk_bf16(c00[e], c10[e]);
                qv.y = cvt_pk_bf16(c01[e], c11[e]);
                qv.z = cvt_pk_bf16(c02[e], c12[e]);
                qv.w = cvt_pk_bf16(c03[e], c13[e]);
                *reinterpret_cast<uint4*>(&smem[rs * PITCHB + xi * 64 + (slot << 4)]) = qv;
            }
        }
        __syncthreads();
    }
}

// ---- smooth: 5x5, 2ch -> 1ch ----
__global__ __launch_bounds__(256) void smooth_kernel(
    const float* __restrict__ sig,
    const float* __restrict__ masks,
    const float* __restrict__ sw,
    const float* __restrict__ sb,
    float* __restrict__ out)
{
    __shared__ float ls[2][400];

    const int tid  = threadIdx.x;
    const int n    = blockIdx.x >> 6;
    const int tile = blockIdx.x & 63;
    const int h0   = (tile >> 3) << 4;
    const int w0   = (tile & 7) << 4;

    for (int i = tid; i < 800; i += 256) {
        int chn = (i >= 400) ? 1 : 0;
        int r  = i - chn * 400;
        int yy = r / 20;
        int xx = r - yy * 20;
        int h  = h0 + yy - 2;
        int w  = w0 + xx - 2;
        float v = 0.0f;
        if ((unsigned)h < 128u && (unsigned)w < 128u) {
            const float* src = chn ? masks : sig;
            v = src[(n << 14) + (h << 7) + w];
        }
        ls[chn][r] = v;
    }
    __syncthreads();

    const int tx = tid & 15;
    const int ty = tid >> 4;

    float accv = sb[0];
    #pragma unroll
    for (int chn = 0; chn < 2; ++chn)
        #pragma unroll
        for (int dy = 0; dy < 5; ++dy)
            #pragma unroll
            for (int dx = 0; dx < 5; ++dx)
                accv = fmaf(ls[chn][(ty + dy) * 20 + tx + dx],
                            sw[(chn * 5 + dy) * 5 + dx], accv);
    out[(n << 14) + ((h0 + ty) << 7) + (w0 + tx)] = accv;
}

extern "C" void kernel_launch(void* const* d_in, const int* in_sizes, int n_in,
                              void* d_out, int out_size, void* d_ws, size_t ws_size,
                              hipStream_t stream) {
    const float* emb     = (const float*)d_in[0];
    const float* inc     = (const float*)d_in[1];
    const float* masks   = (const float*)d_in[2];
    const float* conv_w  = (const float*)d_in[3];
    const float* conv_b  = (const float*)d_in[4];
    const float* bn_g    = (const float*)d_in[5];
    const float* bn_b    = (const float*)d_in[6];
    const float* bn_m    = (const float*)d_in[7];
    const float* bn_v    = (const float*)d_in[8];
    const float* sw      = (const float*)d_in[9];
    const float* sb      = (const float*)d_in[10];
    float*  out   = (float*)d_out;
    float*  sig   = (float*)d_ws;
    ushort* bfrag = (ushort*)((char*)d_ws + BFRAG_OFF);
    float*  shb   = (float*)((char*)d_ws + SH_OFF);
    float*  hdp   = (float*)((char*)d_ws + HDP_OFF);

    prep_kernel<<<54, 256, 0, stream>>>(conv_w, conv_b, bn_g, bn_b, bn_m, bn_v,
                                        inc, bfrag, shb, hdp);
    fused_main_kernel<<<512, 256, 0, stream>>>(emb, bfrag, shb, hdp, sig);
    smooth_kernel<<<2048, 256, 0, stream>>>(sig, masks, sw, sb, out);
}